// Round 3
// baseline (537.183 us; speedup 1.0000x reference)
//
#include <hip/hip_runtime.h>
#include <hip/hip_bf16.h>
#include <stdint.h>

// QuantizedLinear: out_f32[512,16384] = x_f32[512,4096] @ (qw_i32 * scales)^T + bias
// Harness dtype reality (deduced from rounds 1-2 bit patterns):
//   x fp32, qw int32, scales fp32 (fp16-upcast), bias fp32, out fp32.
// bf16 MFMA compute. qw (256 MB) dominates HBM -> read exactly once:
// 256 blocks, each owns BN=64 output cols x ALL 512 rows (8 waves x 64-row strips).
// B dequant (RTN) -> LDS; A pre-converted fp32->bf16 into d_ws by a prepass
// (fallback: convert in-kernel if ws too small); qw prefetched 1 K-block ahead.

#define MM 512
#define NN 16384
#define KK 4096
#define NBLK 64
#define BN 64
#define BK 64
#define LPB 72   // B LDS pitch in ushorts: 64 data + 8 pad

typedef __bf16 bf16x8 __attribute__((ext_vector_type(8)));
typedef float floatx4 __attribute__((ext_vector_type(4)));

// pack two fp32 -> [bf16(hi)|bf16(lo)] with round-to-nearest-even
__device__ __forceinline__ unsigned int pk_bf16_rtn(float lo, float hi) {
    __hip_bfloat162 h = __float22bfloat162_rn(float2{lo, hi});
    return *reinterpret_cast<unsigned int*>(&h);
}

// ---- prepass: x fp32 -> bf16 (RTN) into ws ----
__global__ __launch_bounds__(256) void cvt_x(const float* __restrict__ x,
                                             unsigned short* __restrict__ xb) {
    const int i = (blockIdx.x * 256 + threadIdx.x) * 8;
    const float4 a = *(const float4*)(x + i);
    const float4 b = *(const float4*)(x + i + 4);
    uint4 o;
    o.x = pk_bf16_rtn(a.x, a.y);
    o.y = pk_bf16_rtn(a.z, a.w);
    o.z = pk_bf16_rtn(b.x, b.y);
    o.w = pk_bf16_rtn(b.z, b.w);
    *(uint4*)(xb + i) = o;
}

template <bool PRE>
__global__ __launch_bounds__(512, 2) void qlin_gemm(
    const float* __restrict__ xf,               // fp32 x (fallback path)
    const unsigned short* __restrict__ xb,      // bf16 x (prepass path)
    const int* __restrict__ qw,                 // int32 [16384,4096]
    const float* __restrict__ scales,           // fp32 [16384,64]
    const float* __restrict__ bias,             // fp32 [16384]
    float* __restrict__ out)                    // fp32 [512,16384]
{
    __shared__ unsigned short sB[BN * LPB];

    const int t    = threadIdx.x;
    const int lane = t & 63;
    const int w    = t >> 6;          // wave 0..7 -> M strip [w*64, w*64+64)
    const int n0   = blockIdx.x * BN;
    const int ln   = lane & 15;
    const int quad = lane >> 4;

    // B staging: thread t handles qw row (t>>3), k-octet (t&7)*8
    const int brow = t >> 3;          // 0..63
    const int bcol = (t & 7) * 8;     // 0..56
    const size_t qbase = (size_t)(n0 + brow) * KK + bcol;
    const size_t sbase = (size_t)(n0 + brow) * NBLK;

    floatx4 acc[4][4];
#pragma unroll
    for (int i = 0; i < 4; ++i)
#pragma unroll
        for (int j = 0; j < 4; ++j)
            acc[i][j] = (floatx4)0.0f;

    // prefetch K-block 0
    int4 qv0 = *(const int4*)(qw + qbase);
    int4 qv1 = *(const int4*)(qw + qbase + 4);
    float scb = scales[sbase];

    for (int kb = 0; kb < KK / BK; ++kb) {
        // ---- dequant current K-block into LDS (RTN pack) ----
        const float s = scb;
        uint4 u;
        u.x = pk_bf16_rtn((float)qv0.x * s, (float)qv0.y * s);
        u.y = pk_bf16_rtn((float)qv0.z * s, (float)qv0.w * s);
        u.z = pk_bf16_rtn((float)qv1.x * s, (float)qv1.y * s);
        u.w = pk_bf16_rtn((float)qv1.z * s, (float)qv1.w * s);
        *(uint4*)(&sB[brow * LPB + bcol]) = u;
        __syncthreads();

        // ---- prefetch next K-block of qw (overlaps with MFMA below) ----
        if (kb + 1 < KK / BK) {
            qv0 = *(const int4*)(qw + qbase + (size_t)(kb + 1) * BK);
            qv1 = *(const int4*)(qw + qbase + (size_t)(kb + 1) * BK + 4);
            scb = scales[sbase + kb + 1];
        }

        const int k0 = kb * BK;
        bf16x8 af[2][4], bfr[2][4];
#pragma unroll
        for (int ks = 0; ks < 2; ++ks) {
            const int kofs = k0 + ks * 32 + quad * 8;
#pragma unroll
            for (int i = 0; i < 4; ++i) {
                const size_t rowoff = (size_t)(w * 64 + i * 16 + ln) * KK + kofs;
                if constexpr (PRE) {
                    af[ks][i] = *(const bf16x8*)(xb + rowoff);
                } else {
                    const float4 a0 = *(const float4*)(xf + rowoff);
                    const float4 a1 = *(const float4*)(xf + rowoff + 4);
                    uint4 ua;
                    ua.x = pk_bf16_rtn(a0.x, a0.y);
                    ua.y = pk_bf16_rtn(a0.z, a0.w);
                    ua.z = pk_bf16_rtn(a1.x, a1.y);
                    ua.w = pk_bf16_rtn(a1.z, a1.w);
                    af[ks][i] = *(bf16x8*)&ua;
                }
            }
        }
#pragma unroll
        for (int ks = 0; ks < 2; ++ks) {
            const int kofs = ks * 32 + quad * 8;
#pragma unroll
            for (int j = 0; j < 4; ++j)
                bfr[ks][j] = *(const bf16x8*)(&sB[(j * 16 + ln) * LPB + kofs]);
        }
#pragma unroll
        for (int ks = 0; ks < 2; ++ks)
#pragma unroll
            for (int i = 0; i < 4; ++i)
#pragma unroll
                for (int j = 0; j < 4; ++j)
                    acc[i][j] = __builtin_amdgcn_mfma_f32_16x16x32_bf16(af[ks][i], bfr[ks][j], acc[i][j], 0, 0, 0);
        __syncthreads();
    }

    // ---- epilogue: + bias, store fp32 ----
#pragma unroll
    for (int j = 0; j < 4; ++j) {
        const int n = n0 + j * 16 + ln;
        const float bv = bias[n];
#pragma unroll
        for (int i = 0; i < 4; ++i) {
            const int mbase = w * 64 + i * 16 + quad * 4;
#pragma unroll
            for (int r = 0; r < 4; ++r)
                out[(size_t)(mbase + r) * NN + n] = acc[i][j][r] + bv;
        }
    }
}

extern "C" void kernel_launch(void* const* d_in, const int* in_sizes, int n_in,
                              void* d_out, int out_size, void* d_ws, size_t ws_size,
                              hipStream_t stream) {
    const float* x      = (const float*)d_in[0];
    const int* qw       = (const int*)d_in[1];
    const float* scl    = (const float*)d_in[2];
    const float* bias   = (const float*)d_in[3];
    float* out          = (float*)d_out;

    dim3 block(512);
    dim3 grid(NN / BN);   // 256 blocks, one 64-col slab each, all 512 rows

    if (ws_size >= (size_t)MM * KK * sizeof(unsigned short)) {
        unsigned short* xb = (unsigned short*)d_ws;
        cvt_x<<<dim3(MM * KK / (256 * 8)), dim3(256), 0, stream>>>(x, xb);
        qlin_gemm<true><<<grid, block, 0, stream>>>(x, xb, qw, scl, bias, out);
    } else {
        qlin_gemm<false><<<grid, block, 0, stream>>>(x, nullptr, qw, scl, bias, out);
    }
}

// Round 4
// 453.955 us; speedup vs baseline: 1.1833x; 1.1833x over previous
//
#include <hip/hip_runtime.h>
#include <hip/hip_bf16.h>
#include <stdint.h>

// QuantizedLinear: out_f32[512,16384] = x_f32[512,4096] @ (qw_i32 * scales)^T + bias
// dtypes (verified round 3): x fp32, qw int32, scales fp32, bias fp32, out fp32.
//
// Round-4 structure: latency-bound fix.
//  - grid 256 x 1024 threads (16 waves/CU, 4/SIMD) -> occupancy 50% vs 23%.
//  - qw (256 MB) read exactly once: block = BN=64 output cols x all 512 rows.
//  - BK=128, double-buffered B LDS, ONE barrier/iter, 1-deep qw register prefetch.
//  - prepass packs x fp32->bf16 in MFMA-fragment order so every A-load is one
//    fully-coalesced 1KB wave load (was a 16-segment gather).

#define MM 512
#define NN 16384
#define KK 4096
#define BN 64
#define BK 128
#define NKB (KK / BK)   // 32

typedef __bf16 bf16x8 __attribute__((ext_vector_type(8)));
typedef float floatx4 __attribute__((ext_vector_type(4)));

__device__ __forceinline__ unsigned int pk_bf16_rtn(float lo, float hi) {
    __hip_bfloat162 h = __float22bfloat162_rn(float2{lo, hi});
    return *reinterpret_cast<unsigned int*>(&h);
}

// ---- prepass: x fp32 -> bf16, packed in MFMA A-fragment order ----
// xp element index: (((kb*4 + ks)*32 + mt)*64 + lane)*8,
//   holding x[mt*16 + (lane&15)][kb*128 + ks*32 + (lane>>4)*8 .. +8]
__global__ __launch_bounds__(256) void pack_x(const float* __restrict__ x,
                                              unsigned short* __restrict__ xp) {
    const int t    = blockIdx.x * 256 + threadIdx.x;   // 0..262143
    const int lane = t & 63;
    const int mt   = (t >> 6) & 31;
    const int ks   = (t >> 11) & 3;
    const int kb   = t >> 13;
    const int m    = mt * 16 + (lane & 15);
    const int k    = kb * 128 + ks * 32 + (lane >> 4) * 8;
    const float* px = x + (size_t)m * KK + k;
    const float4 a = *(const float4*)px;
    const float4 b = *(const float4*)(px + 4);
    uint4 o;
    o.x = pk_bf16_rtn(a.x, a.y);
    o.y = pk_bf16_rtn(a.z, a.w);
    o.z = pk_bf16_rtn(b.x, b.y);
    o.w = pk_bf16_rtn(b.z, b.w);
    *(uint4*)(xp + (size_t)t * 8) = o;   // fully coalesced 16B/thread
}

template <bool PRE>
__global__ __launch_bounds__(1024, 4) void qlin_gemm(
    const float* __restrict__ xf,               // fp32 x (fallback path)
    const unsigned short* __restrict__ xp,      // packed bf16 x (prepass path)
    const int* __restrict__ qw,                 // int32 [16384,4096]
    const float* __restrict__ scales,           // fp32 [16384,64]
    const float* __restrict__ bias,             // fp32 [16384]
    float* __restrict__ out)                    // fp32 [512,16384]
{
    __shared__ unsigned short sB[2][BN * BK];   // 2 x 16 KB

    const int t    = threadIdx.x;
    const int lane = t & 63;
    const int w    = t >> 6;          // wave 0..15 -> M strip [w*32, w*32+32)
    const int ln   = lane & 15;
    const int quad = lane >> 4;
    const int n0   = blockIdx.x * BN;

    // B staging: thread t -> qw row (t>>4), 4-col chunk (t&15)*4 in each 64-half
    const int brow = t >> 4;          // 0..63
    const int bk4  = (t & 15) * 4;    // 0..60
    const int* qp0 = qw + (size_t)(n0 + brow) * KK + bk4;        // k-half 0
    const int* qp1 = qp0 + 64;                                    // k-half 1
    const float2* sp = (const float2*)(scales + (size_t)(n0 + brow) * 64);

    floatx4 acc[2][4];
#pragma unroll
    for (int i = 0; i < 2; ++i)
#pragma unroll
        for (int j = 0; j < 4; ++j)
            acc[i][j] = (floatx4)0.0f;

    // prefetch K-block 0 (fully coalesced: 16 lanes x 16B contiguous per inst)
    int4 qv0 = *(const int4*)(qp0);
    int4 qv1 = *(const int4*)(qp1);
    float2 ss = sp[0];

    for (int kb = 0; kb < NKB; ++kb) {
        unsigned short* sb = sB[kb & 1];
        // ---- dequant prefetched qw K-block into LDS (RTN, exact for pow2*scale) ----
        uint2 u0, u1;
        u0.x = pk_bf16_rtn((float)qv0.x * ss.x, (float)qv0.y * ss.x);
        u0.y = pk_bf16_rtn((float)qv0.z * ss.x, (float)qv0.w * ss.x);
        u1.x = pk_bf16_rtn((float)qv1.x * ss.y, (float)qv1.y * ss.y);
        u1.y = pk_bf16_rtn((float)qv1.z * ss.y, (float)qv1.w * ss.y);
        *(uint2*)(sb + brow * BK + bk4)      = u0;
        *(uint2*)(sb + brow * BK + 64 + bk4) = u1;

        // ---- issue next K-block's qw loads (keeps HBM stream independent) ----
        if (kb + 1 < NKB) {
            qv0 = *(const int4*)(qp0 + (size_t)(kb + 1) * BK);
            qv1 = *(const int4*)(qp1 + (size_t)(kb + 1) * BK);
            ss  = sp[kb + 1];
        }

        __syncthreads();   // single barrier per iter (double-buffered LDS)

        const unsigned short* xpb = xp + (size_t)kb * (4 * 32 * 64 * 8);
#pragma unroll
        for (int ks = 0; ks < 4; ++ks) {
            bf16x8 a0, a1;
            if constexpr (PRE) {
                const unsigned short* ap = xpb + (size_t)((ks * 32 + w * 2) * 64 + lane) * 8;
                a0 = *(const bf16x8*)(ap);            // 1KB coalesced wave load
                a1 = *(const bf16x8*)(ap + 64 * 8);
            } else {
                const int k = kb * BK + ks * 32 + quad * 8;
#pragma unroll
                for (int i = 0; i < 2; ++i) {
                    const float* px = xf + (size_t)(w * 32 + i * 16 + ln) * KK + k;
                    const float4 f0 = *(const float4*)px;
                    const float4 f1 = *(const float4*)(px + 4);
                    uint4 ua;
                    ua.x = pk_bf16_rtn(f0.x, f0.y);
                    ua.y = pk_bf16_rtn(f0.z, f0.w);
                    ua.z = pk_bf16_rtn(f1.x, f1.y);
                    ua.w = pk_bf16_rtn(f1.z, f1.w);
                    if (i == 0) a0 = *(bf16x8*)&ua; else a1 = *(bf16x8*)&ua;
                }
            }
            bf16x8 bfr[4];
#pragma unroll
            for (int j = 0; j < 4; ++j)
                bfr[j] = *(const bf16x8*)(sb + (j * 16 + ln) * BK + ks * 32 + quad * 8);
#pragma unroll
            for (int j = 0; j < 4; ++j) {
                acc[0][j] = __builtin_amdgcn_mfma_f32_16x16x32_bf16(a0, bfr[j], acc[0][j], 0, 0, 0);
                acc[1][j] = __builtin_amdgcn_mfma_f32_16x16x32_bf16(a1, bfr[j], acc[1][j], 0, 0, 0);
            }
        }
        // no trailing barrier: next iter writes the OTHER LDS buffer
    }

    // ---- epilogue: + bias, store fp32 ----
#pragma unroll
    for (int j = 0; j < 4; ++j) {
        const int n = n0 + j * 16 + ln;
        const float bv = bias[n];
#pragma unroll
        for (int i = 0; i < 2; ++i) {
            const int mbase = w * 32 + i * 16 + quad * 4;
#pragma unroll
            for (int r = 0; r < 4; ++r)
                out[(size_t)(mbase + r) * NN + n] = acc[i][j][r] + bv;
        }
    }
}

extern "C" void kernel_launch(void* const* d_in, const int* in_sizes, int n_in,
                              void* d_out, int out_size, void* d_ws, size_t ws_size,
                              hipStream_t stream) {
    const float* x    = (const float*)d_in[0];
    const int* qw     = (const int*)d_in[1];
    const float* scl  = (const float*)d_in[2];
    const float* bias = (const float*)d_in[3];
    float* out        = (float*)d_out;

    dim3 grid(NN / BN);    // 256 blocks: one 64-col slab each, all 512 rows
    dim3 block(1024);      // 16 waves

    if (ws_size >= (size_t)MM * KK * sizeof(unsigned short)) {
        unsigned short* xp = (unsigned short*)d_ws;
        pack_x<<<dim3(MM * KK / (256 * 8)), dim3(256), 0, stream>>>(x, xp);
        qlin_gemm<true><<<grid, block, 0, stream>>>(x, xp, qw, scl, bias, out);
    } else {
        qlin_gemm<false><<<grid, block, 0, stream>>>(x, nullptr, qw, scl, bias, out);
    }
}

// Round 5
// 421.590 us; speedup vs baseline: 1.2742x; 1.0768x over previous
//
#include <hip/hip_runtime.h>
#include <hip/hip_bf16.h>
#include <stdint.h>

// QuantizedLinear: out_f32[512,16384] = x_f32[512,4096] @ (qw_i32 * scales)^T + bias
// dtypes (verified round 3): x fp32, qw int32, scales fp32, bias fp32, out fp32.
//
// Round-5: kill the 16-way LDS bank conflict that was the round-4 wall.
// B is stored in LDS in MFMA-fragment order with an XOR swizzle:
//   slot(ks, j, lane) = ((ks*4 + j)*64 + (lane ^ (ks<<1))) * 8 ushorts
// Producer thread t dequants row (t>>4), k-octet (t&15) -> exactly one
// fragment-lane's 8 elems -> one ds_write_b128; consumer ds_read_b128 is
// bank-sequential. Both sides verified 2 lanes/bank (free).
// Everything else = round 4: grid 256 x 1024, qw read once, BK=128,
// double-buffered LDS, 1 barrier/iter, 1-deep qw register prefetch,
// x pre-packed fp32->bf16 in fragment order (coalesced 1KB A-loads).

#define MM 512
#define NN 16384
#define KK 4096
#define BN 64
#define BK 128
#define NKB (KK / BK)   // 32

typedef __bf16 bf16x8 __attribute__((ext_vector_type(8)));
typedef float floatx4 __attribute__((ext_vector_type(4)));

__device__ __forceinline__ unsigned int pk_bf16_rtn(float lo, float hi) {
    __hip_bfloat162 h = __float22bfloat162_rn(float2{lo, hi});
    return *reinterpret_cast<unsigned int*>(&h);
}

// ---- prepass: x fp32 -> bf16, packed in MFMA A-fragment order ----
// xp element index: (((kb*4 + ks)*32 + mt)*64 + lane)*8,
//   holding x[mt*16 + (lane&15)][kb*128 + ks*32 + (lane>>4)*8 .. +8]
__global__ __launch_bounds__(256) void pack_x(const float* __restrict__ x,
                                              unsigned short* __restrict__ xp) {
    const int t    = blockIdx.x * 256 + threadIdx.x;   // 0..262143
    const int lane = t & 63;
    const int mt   = (t >> 6) & 31;
    const int ks   = (t >> 11) & 3;
    const int kb   = t >> 13;
    const int m    = mt * 16 + (lane & 15);
    const int k    = kb * 128 + ks * 32 + (lane >> 4) * 8;
    const float* px = x + (size_t)m * KK + k;
    const float4 a = *(const float4*)px;
    const float4 b = *(const float4*)(px + 4);
    uint4 o;
    o.x = pk_bf16_rtn(a.x, a.y);
    o.y = pk_bf16_rtn(a.z, a.w);
    o.z = pk_bf16_rtn(b.x, b.y);
    o.w = pk_bf16_rtn(b.z, b.w);
    *(uint4*)(xp + (size_t)t * 8) = o;   // fully coalesced 16B/thread
}

template <bool PRE>
__global__ __launch_bounds__(1024, 4) void qlin_gemm(
    const float* __restrict__ xf,               // fp32 x (fallback path)
    const unsigned short* __restrict__ xp,      // packed bf16 x (prepass path)
    const int* __restrict__ qw,                 // int32 [16384,4096]
    const float* __restrict__ scales,           // fp32 [16384,64]
    const float* __restrict__ bias,             // fp32 [16384]
    float* __restrict__ out)                    // fp32 [512,16384]
{
    __shared__ unsigned short sB[2][BN * BK];   // fragment-ordered + swizzled, 2 x 16 KB

    const int t    = threadIdx.x;
    const int lane = t & 63;
    const int w    = t >> 6;          // wave 0..15 -> M strip [w*32, w*32+32)
    const int ln   = lane & 15;
    const int quad = lane >> 4;
    const int n0   = blockIdx.x * BN;

    // ---- producer mapping: thread t -> qw row (t>>4), k-octet (t&15) ----
    const int r    = t >> 4;          // 0..63
    const int oct  = t & 15;          // which 8-wide k chunk of the 128
    const int ksp  = oct >> 2;        // frag k-slice 0..3
    const int jp   = r >> 4;          // frag col-tile 0..3
    const int ldst = (((oct & 3) << 4) + (r & 15)) ^ (ksp << 1);   // swizzled frag lane
    const int woff = ((ksp * 4 + jp) * 64 + ldst) * 8;
    const int* qp  = qw + (size_t)(n0 + r) * KK + oct * 8;
    const float* sp = scales + (size_t)(n0 + r) * 64 + (oct >> 3);

    floatx4 acc[2][4];
#pragma unroll
    for (int i = 0; i < 2; ++i)
#pragma unroll
        for (int j = 0; j < 4; ++j)
            acc[i][j] = (floatx4)0.0f;

    // prefetch K-block 0
    int4 qv0 = *(const int4*)(qp);
    int4 qv1 = *(const int4*)(qp + 4);
    float s  = sp[0];

    for (int kb = 0; kb < NKB; ++kb) {
        unsigned short* sb = sB[kb & 1];
        // ---- dequant prefetched qw K-block straight into its fragment slot ----
        uint4 u;
        u.x = pk_bf16_rtn((float)qv0.x * s, (float)qv0.y * s);
        u.y = pk_bf16_rtn((float)qv0.z * s, (float)qv0.w * s);
        u.z = pk_bf16_rtn((float)qv1.x * s, (float)qv1.y * s);
        u.w = pk_bf16_rtn((float)qv1.z * s, (float)qv1.w * s);
        *(uint4*)(sb + woff) = u;     // one conflict-free ds_write_b128

        // ---- issue next K-block's qw loads (HBM stream stays ahead) ----
        if (kb + 1 < NKB) {
            qv0 = *(const int4*)(qp + (size_t)(kb + 1) * BK);
            qv1 = *(const int4*)(qp + (size_t)(kb + 1) * BK + 4);
            s   = sp[(size_t)(kb + 1) * 2];
        }

        __syncthreads();   // single barrier per iter (double-buffered LDS)

        // ---- A fragments (global, coalesced 1KB wave loads), hoisted for ILP ----
        bf16x8 a[4][2];
        const unsigned short* xpb = xp + (size_t)kb * (4 * 32 * 64 * 8);
#pragma unroll
        for (int ks = 0; ks < 4; ++ks) {
            if constexpr (PRE) {
                const unsigned short* ap = xpb + (size_t)((ks * 32 + w * 2) * 64 + lane) * 8;
                a[ks][0] = *(const bf16x8*)(ap);
                a[ks][1] = *(const bf16x8*)(ap + 512);
            } else {
                const int k = kb * BK + ks * 32 + quad * 8;
#pragma unroll
                for (int i = 0; i < 2; ++i) {
                    const float* px = xf + (size_t)(w * 32 + i * 16 + ln) * KK + k;
                    const float4 f0 = *(const float4*)px;
                    const float4 f1 = *(const float4*)(px + 4);
                    uint4 ua;
                    ua.x = pk_bf16_rtn(f0.x, f0.y);
                    ua.y = pk_bf16_rtn(f0.z, f0.w);
                    ua.z = pk_bf16_rtn(f1.x, f1.y);
                    ua.w = pk_bf16_rtn(f1.z, f1.w);
                    a[ks][i] = *(bf16x8*)&ua;
                }
            }
        }
#pragma unroll
        for (int ks = 0; ks < 4; ++ks) {
            bf16x8 bfr[4];
#pragma unroll
            for (int j = 0; j < 4; ++j)
                bfr[j] = *(const bf16x8*)(sb + ((ks * 4 + j) * 64 + (lane ^ (ks << 1))) * 8);
#pragma unroll
            for (int j = 0; j < 4; ++j) {
                acc[0][j] = __builtin_amdgcn_mfma_f32_16x16x32_bf16(a[ks][0], bfr[j], acc[0][j], 0, 0, 0);
                acc[1][j] = __builtin_amdgcn_mfma_f32_16x16x32_bf16(a[ks][1], bfr[j], acc[1][j], 0, 0, 0);
            }
        }
        // no trailing barrier: next iter writes the OTHER LDS buffer
    }

    // ---- epilogue: + bias, store fp32 ----
#pragma unroll
    for (int j = 0; j < 4; ++j) {
        const int n = n0 + j * 16 + ln;
        const float bv = bias[n];
#pragma unroll
        for (int i = 0; i < 2; ++i) {
            const int mbase = w * 32 + i * 16 + quad * 4;
#pragma unroll
            for (int rr = 0; rr < 4; ++rr)
                out[(size_t)(mbase + rr) * NN + n] = acc[i][j][rr] + bv;
        }
    }
}

extern "C" void kernel_launch(void* const* d_in, const int* in_sizes, int n_in,
                              void* d_out, int out_size, void* d_ws, size_t ws_size,
                              hipStream_t stream) {
    const float* x    = (const float*)d_in[0];
    const int* qw     = (const int*)d_in[1];
    const float* scl  = (const float*)d_in[2];
    const float* bias = (const float*)d_in[3];
    float* out        = (float*)d_out;

    dim3 grid(NN / BN);    // 256 blocks: one 64-col slab each, all 512 rows
    dim3 block(1024);      // 16 waves

    if (ws_size >= (size_t)MM * KK * sizeof(unsigned short)) {
        unsigned short* xp = (unsigned short*)d_ws;
        pack_x<<<dim3(MM * KK / (256 * 8)), dim3(256), 0, stream>>>(x, xp);
        qlin_gemm<true><<<grid, block, 0, stream>>>(x, xp, qw, scl, bias, out);
    } else {
        qlin_gemm<false><<<grid, block, 0, stream>>>(x, nullptr, qw, scl, bias, out);
    }
}

// Round 6
// 418.846 us; speedup vs baseline: 1.2825x; 1.0066x over previous
//
#include <hip/hip_runtime.h>
#include <hip/hip_bf16.h>
#include <stdint.h>

// QuantizedLinear: out_f32[512,16384] = x_f32[512,4096] @ (qw_i32 * scales)^T + bias
// dtypes (verified round 3): x fp32, qw int32, scales fp32, bias fp32, out fp32.
//
// Round-6: software-pipeline across the barrier.
// The round-5 wall: qw prefetch + A loads were issued just before / right at
// their use, and __syncthreads' vmcnt(0) drain exposed ~full HBM latency every
// iteration for all waves in lockstep. Now BOTH next-iter streams (qw, A) are
// issued immediately AFTER the barrier and consumed one full compute phase
// (~3000 cyc) later -> barrier drain ~0, no first-use stalls.
//   - grid 256 x 1024 (1 block/CU), qw (256 MB) read exactly once
//   - BK=128, double-buffered swizzled fragment-order B in LDS (conflict-free,
//     verified round 5: 5.9e7 -> noise)
//   - A double-buffered in registers from the fragment-order packed-x prepass

#define MM 512
#define NN 16384
#define KK 4096
#define BN 64
#define BK 128
#define NKB (KK / BK)   // 32

typedef __bf16 bf16x8 __attribute__((ext_vector_type(8)));
typedef float floatx4 __attribute__((ext_vector_type(4)));

__device__ __forceinline__ unsigned int pk_bf16_rtn(float lo, float hi) {
    __hip_bfloat162 h = __float22bfloat162_rn(float2{lo, hi});
    return *reinterpret_cast<unsigned int*>(&h);
}

// ---- prepass: x fp32 -> bf16, packed in MFMA A-fragment order ----
// xp element index: (((kb*4 + ks)*32 + mt)*64 + lane)*8,
//   holding x[mt*16 + (lane&15)][kb*128 + ks*32 + (lane>>4)*8 .. +8]
__global__ __launch_bounds__(256) void pack_x(const float* __restrict__ x,
                                              unsigned short* __restrict__ xp) {
    const int t    = blockIdx.x * 256 + threadIdx.x;   // 0..262143
    const int lane = t & 63;
    const int mt   = (t >> 6) & 31;
    const int ks   = (t >> 11) & 3;
    const int kb   = t >> 13;
    const int m    = mt * 16 + (lane & 15);
    const int k    = kb * 128 + ks * 32 + (lane >> 4) * 8;
    const float* px = x + (size_t)m * KK + k;
    const float4 a = *(const float4*)px;
    const float4 b = *(const float4*)(px + 4);
    uint4 o;
    o.x = pk_bf16_rtn(a.x, a.y);
    o.y = pk_bf16_rtn(a.z, a.w);
    o.z = pk_bf16_rtn(b.x, b.y);
    o.w = pk_bf16_rtn(b.z, b.w);
    *(uint4*)(xp + (size_t)t * 8) = o;   // fully coalesced 16B/thread
}

template <bool PRE>
__global__ __launch_bounds__(1024, 4) void qlin_gemm(
    const float* __restrict__ xf,               // fp32 x (fallback path)
    const unsigned short* __restrict__ xp,      // packed bf16 x (prepass path)
    const int* __restrict__ qw,                 // int32 [16384,4096]
    const float* __restrict__ scales,           // fp32 [16384,64]
    const float* __restrict__ bias,             // fp32 [16384]
    float* __restrict__ out)                    // fp32 [512,16384]
{
    __shared__ unsigned short sB[2][BN * BK];   // fragment-ordered + swizzled, 2 x 16 KB

    const int t    = threadIdx.x;
    const int lane = t & 63;
    const int w    = t >> 6;          // wave 0..15 -> M strip [w*32, w*32+32)
    const int ln   = lane & 15;
    const int quad = lane >> 4;
    const int n0   = blockIdx.x * BN;

    // ---- producer mapping: thread t -> qw row (t>>4), k-octet (t&15) ----
    const int r    = t >> 4;          // 0..63
    const int oct  = t & 15;
    const int ksp  = oct >> 2;        // frag k-slice 0..3
    const int jp   = r >> 4;          // frag col-tile 0..3
    const int ldst = (((oct & 3) << 4) | (r & 15)) ^ (ksp << 1);   // swizzled frag lane
    const int woff = ((ksp * 4 + jp) * 64 + ldst) * 8;
    const int* qp  = qw + (size_t)(n0 + r) * KK + oct * 8;
    const float* sp = scales + (size_t)(n0 + r) * 64 + (oct >> 3);

    floatx4 acc[2][4];
#pragma unroll
    for (int i = 0; i < 2; ++i)
#pragma unroll
        for (int j = 0; j < 4; ++j)
            acc[i][j] = (floatx4)0.0f;

    // ---- prologue: qw(0) + A(0) in flight ----
    int4 qv0 = *(const int4*)(qp);
    int4 qv1 = *(const int4*)(qp + 4);
    float s  = sp[0];

    bf16x8 a[2][4][2];   // [buf][ks][i] -- A register double-buffer
    if constexpr (PRE) {
#pragma unroll
        for (int ks = 0; ks < 4; ++ks) {
            const unsigned short* ap = xp + (size_t)((ks * 32 + w * 2) * 64 + lane) * 8;
            a[0][ks][0] = *(const bf16x8*)(ap);
            a[0][ks][1] = *(const bf16x8*)(ap + 512);
        }
    }

#pragma unroll 2
    for (int kb = 0; kb < NKB; ++kb) {
        const int cur = kb & 1;
        unsigned short* sb = sB[cur];

        // ---- dequant qw(kb) (loaded one full iteration ago) into LDS ----
        uint4 u;
        u.x = pk_bf16_rtn((float)qv0.x * s, (float)qv0.y * s);
        u.y = pk_bf16_rtn((float)qv0.z * s, (float)qv0.w * s);
        u.z = pk_bf16_rtn((float)qv1.x * s, (float)qv1.y * s);
        u.w = pk_bf16_rtn((float)qv1.z * s, (float)qv1.w * s);
        *(uint4*)(sb + woff) = u;     // one conflict-free ds_write_b128

        __syncthreads();   // drains nothing in flight (prefetches issued post-barrier)

        // ---- issue NEXT iteration's streams now; consume after ~3000 cyc ----
        if (kb + 1 < NKB) {
            qv0 = *(const int4*)(qp + (size_t)(kb + 1) * BK);
            qv1 = *(const int4*)(qp + (size_t)(kb + 1) * BK + 4);
            s   = sp[(size_t)(kb + 1) * 2];
            if constexpr (PRE) {
                const unsigned short* xpb = xp + (size_t)(kb + 1) * (4 * 32 * 64 * 8);
#pragma unroll
                for (int ks = 0; ks < 4; ++ks) {
                    const unsigned short* ap = xpb + (size_t)((ks * 32 + w * 2) * 64 + lane) * 8;
                    a[cur ^ 1][ks][0] = *(const bf16x8*)(ap);
                    a[cur ^ 1][ks][1] = *(const bf16x8*)(ap + 512);
                }
            }
        }

        // ---- compute kb from LDS B + register A ----
#pragma unroll
        for (int ks = 0; ks < 4; ++ks) {
            bf16x8 a0, a1;
            if constexpr (PRE) {
                a0 = a[cur][ks][0];
                a1 = a[cur][ks][1];
            } else {
                const int k = kb * BK + ks * 32 + quad * 8;
#pragma unroll
                for (int i = 0; i < 2; ++i) {
                    const float* px = xf + (size_t)(w * 32 + i * 16 + ln) * KK + k;
                    const float4 f0 = *(const float4*)px;
                    const float4 f1 = *(const float4*)(px + 4);
                    uint4 ua;
                    ua.x = pk_bf16_rtn(f0.x, f0.y);
                    ua.y = pk_bf16_rtn(f0.z, f0.w);
                    ua.z = pk_bf16_rtn(f1.x, f1.y);
                    ua.w = pk_bf16_rtn(f1.z, f1.w);
                    if (i == 0) a0 = *(bf16x8*)&ua; else a1 = *(bf16x8*)&ua;
                }
            }
            bf16x8 bfr[4];
#pragma unroll
            for (int j = 0; j < 4; ++j)
                bfr[j] = *(const bf16x8*)(sb + ((ks * 4 + j) * 64 + (lane ^ (ks << 1))) * 8);
#pragma unroll
            for (int j = 0; j < 4; ++j) {
                acc[0][j] = __builtin_amdgcn_mfma_f32_16x16x32_bf16(a0, bfr[j], acc[0][j], 0, 0, 0);
                acc[1][j] = __builtin_amdgcn_mfma_f32_16x16x32_bf16(a1, bfr[j], acc[1][j], 0, 0, 0);
            }
        }
        // no trailing barrier: next iter writes the OTHER LDS buffer
    }

    // ---- epilogue: + bias, store fp32 ----
#pragma unroll
    for (int j = 0; j < 4; ++j) {
        const int n = n0 + j * 16 + ln;
        const float bv = bias[n];
#pragma unroll
        for (int i = 0; i < 2; ++i) {
            const int mbase = w * 32 + i * 16 + quad * 4;
#pragma unroll
            for (int rr = 0; rr < 4; ++rr)
                out[(size_t)(mbase + rr) * NN + n] = acc[i][j][rr] + bv;
        }
    }
}

extern "C" void kernel_launch(void* const* d_in, const int* in_sizes, int n_in,
                              void* d_out, int out_size, void* d_ws, size_t ws_size,
                              hipStream_t stream) {
    const float* x    = (const float*)d_in[0];
    const int* qw     = (const int*)d_in[1];
    const float* scl  = (const float*)d_in[2];
    const float* bias = (const float*)d_in[3];
    float* out        = (float*)d_out;

    dim3 grid(NN / BN);    // 256 blocks: one 64-col slab each, all 512 rows
    dim3 block(1024);      // 16 waves

    if (ws_size >= (size_t)MM * KK * sizeof(unsigned short)) {
        unsigned short* xp = (unsigned short*)d_ws;
        pack_x<<<dim3(MM * KK / (256 * 8)), dim3(256), 0, stream>>>(x, xp);
        qlin_gemm<true><<<grid, block, 0, stream>>>(x, xp, qw, scl, bias, out);
    } else {
        qlin_gemm<false><<<grid, block, 0, stream>>>(x, nullptr, qw, scl, bias, out);
    }
}

// Round 7
// 418.519 us; speedup vs baseline: 1.2835x; 1.0008x over previous
//
#include <hip/hip_runtime.h>
#include <hip/hip_bf16.h>
#include <stdint.h>

// QuantizedLinear: out_f32[512,16384] = x_f32[512,4096] @ (qw_i32 * scales)^T + bias
// dtypes (verified round 3): x fp32, qw int32, scales fp32, bias fp32, out fp32.
//
// Round-7: break the vmcnt(0) barrier drain.
// Round-6 forensics: per-iter cycles (~11k/CU) == SUM of all pipes (LDS 3.3k +
// MFMA 2.5k + qw HBM wire 3.1k + A L2 2.3k) -> zero overlap. Cause: HIP
// __syncthreads emits s_waitcnt vmcnt(0) before s_barrier, draining the
// prefetch streams every iteration (m97 plateau mechanism). Fix: raw barrier
// with ONLY lgkmcnt(0) (covers the LDS write handoff); global loads stay in
// flight across the barrier, compiler still inserts vmcnt(N) at first use.
// Everything else identical to round 6 (passed, absmax 0.125):
//   grid 256 x 1024, qw read once, BK=128, double-buffered swizzled
//   fragment-order B in LDS (conflict-free), A register-double-buffered from
//   the fragment-order packed-x prepass.

#define MM 512
#define NN 16384
#define KK 4096
#define BN 64
#define BK 128
#define NKB (KK / BK)   // 32

typedef __bf16 bf16x8 __attribute__((ext_vector_type(8)));
typedef float floatx4 __attribute__((ext_vector_type(4)));

__device__ __forceinline__ void barrier_nodrain() {
    // LDS handoff needs lgkmcnt(0); deliberately NO vmcnt drain.
    asm volatile("s_waitcnt lgkmcnt(0)\n\ts_barrier" ::: "memory");
}

__device__ __forceinline__ unsigned int pk_bf16_rtn(float lo, float hi) {
    __hip_bfloat162 h = __float22bfloat162_rn(float2{lo, hi});
    return *reinterpret_cast<unsigned int*>(&h);
}

// ---- prepass: x fp32 -> bf16, packed in MFMA A-fragment order ----
// xp element index: (((kb*4 + ks)*32 + mt)*64 + lane)*8,
//   holding x[mt*16 + (lane&15)][kb*128 + ks*32 + (lane>>4)*8 .. +8]
__global__ __launch_bounds__(256) void pack_x(const float* __restrict__ x,
                                              unsigned short* __restrict__ xp) {
    const int t    = blockIdx.x * 256 + threadIdx.x;   // 0..262143
    const int lane = t & 63;
    const int mt   = (t >> 6) & 31;
    const int ks   = (t >> 11) & 3;
    const int kb   = t >> 13;
    const int m    = mt * 16 + (lane & 15);
    const int k    = kb * 128 + ks * 32 + (lane >> 4) * 8;
    const float* px = x + (size_t)m * KK + k;
    const float4 a = *(const float4*)px;
    const float4 b = *(const float4*)(px + 4);
    uint4 o;
    o.x = pk_bf16_rtn(a.x, a.y);
    o.y = pk_bf16_rtn(a.z, a.w);
    o.z = pk_bf16_rtn(b.x, b.y);
    o.w = pk_bf16_rtn(b.z, b.w);
    *(uint4*)(xp + (size_t)t * 8) = o;   // fully coalesced 16B/thread
}

template <bool PRE>
__global__ __launch_bounds__(1024, 4) void qlin_gemm(
    const float* __restrict__ xf,               // fp32 x (fallback path)
    const unsigned short* __restrict__ xp,      // packed bf16 x (prepass path)
    const int* __restrict__ qw,                 // int32 [16384,4096]
    const float* __restrict__ scales,           // fp32 [16384,64]
    const float* __restrict__ bias,             // fp32 [16384]
    float* __restrict__ out)                    // fp32 [512,16384]
{
    __shared__ unsigned short sB[2][BN * BK];   // fragment-ordered + swizzled, 2 x 16 KB

    const int t    = threadIdx.x;
    const int lane = t & 63;
    const int w    = t >> 6;          // wave 0..15 -> M strip [w*32, w*32+32)
    const int ln   = lane & 15;
    const int quad = lane >> 4;
    const int n0   = blockIdx.x * BN;

    // ---- producer mapping: thread t -> qw row (t>>4), k-octet (t&15) ----
    const int r    = t >> 4;          // 0..63
    const int oct  = t & 15;
    const int ksp  = oct >> 2;        // frag k-slice 0..3
    const int jp   = r >> 4;          // frag col-tile 0..3
    const int ldst = (((oct & 3) << 4) | (r & 15)) ^ (ksp << 1);   // swizzled frag lane
    const int woff = ((ksp * 4 + jp) * 64 + ldst) * 8;
    const int* qp  = qw + (size_t)(n0 + r) * KK + oct * 8;
    const float* sp = scales + (size_t)(n0 + r) * 64 + (oct >> 3);

    floatx4 acc[2][4];
#pragma unroll
    for (int i = 0; i < 2; ++i)
#pragma unroll
        for (int j = 0; j < 4; ++j)
            acc[i][j] = (floatx4)0.0f;

    // ---- prologue: qw(0) + A(0) in flight ----
    int4 qv0 = *(const int4*)(qp);
    int4 qv1 = *(const int4*)(qp + 4);
    float s  = sp[0];

    bf16x8 a[2][4][2];   // [buf][ks][i] -- A register double-buffer
    if constexpr (PRE) {
#pragma unroll
        for (int ks = 0; ks < 4; ++ks) {
            const unsigned short* ap = xp + (size_t)((ks * 32 + w * 2) * 64 + lane) * 8;
            a[0][ks][0] = *(const bf16x8*)(ap);
            a[0][ks][1] = *(const bf16x8*)(ap + 512);
        }
    }

#pragma unroll 2
    for (int kb = 0; kb < NKB; ++kb) {
        const int cur = kb & 1;
        unsigned short* sb = sB[cur];

        // ---- dequant qw(kb) (loaded one full iteration ago) into LDS ----
        uint4 u;
        u.x = pk_bf16_rtn((float)qv0.x * s, (float)qv0.y * s);
        u.y = pk_bf16_rtn((float)qv0.z * s, (float)qv0.w * s);
        u.z = pk_bf16_rtn((float)qv1.x * s, (float)qv1.y * s);
        u.w = pk_bf16_rtn((float)qv1.z * s, (float)qv1.w * s);
        *(uint4*)(sb + woff) = u;     // one conflict-free ds_write_b128

        barrier_nodrain();   // lgkm drain only -- global streams stay in flight

        // ---- issue NEXT iteration's streams; wire time overlaps this compute ----
        if (kb + 1 < NKB) {
            qv0 = *(const int4*)(qp + (size_t)(kb + 1) * BK);
            qv1 = *(const int4*)(qp + (size_t)(kb + 1) * BK + 4);
            s   = sp[(size_t)(kb + 1) * 2];
            if constexpr (PRE) {
                const unsigned short* xpb = xp + (size_t)(kb + 1) * (4 * 32 * 64 * 8);
#pragma unroll
                for (int ks = 0; ks < 4; ++ks) {
                    const unsigned short* ap = xpb + (size_t)((ks * 32 + w * 2) * 64 + lane) * 8;
                    a[cur ^ 1][ks][0] = *(const bf16x8*)(ap);
                    a[cur ^ 1][ks][1] = *(const bf16x8*)(ap + 512);
                }
            }
        }

        // ---- compute kb from LDS B + register A ----
#pragma unroll
        for (int ks = 0; ks < 4; ++ks) {
            bf16x8 a0, a1;
            if constexpr (PRE) {
                a0 = a[cur][ks][0];
                a1 = a[cur][ks][1];
            } else {
                const int k = kb * BK + ks * 32 + quad * 8;
#pragma unroll
                for (int i = 0; i < 2; ++i) {
                    const float* px = xf + (size_t)(w * 32 + i * 16 + ln) * KK + k;
                    const float4 f0 = *(const float4*)px;
                    const float4 f1 = *(const float4*)(px + 4);
                    uint4 ua;
                    ua.x = pk_bf16_rtn(f0.x, f0.y);
                    ua.y = pk_bf16_rtn(f0.z, f0.w);
                    ua.z = pk_bf16_rtn(f1.x, f1.y);
                    ua.w = pk_bf16_rtn(f1.z, f1.w);
                    if (i == 0) a0 = *(bf16x8*)&ua; else a1 = *(bf16x8*)&ua;
                }
            }
            bf16x8 bfr[4];
#pragma unroll
            for (int j = 0; j < 4; ++j)
                bfr[j] = *(const bf16x8*)(sb + ((ks * 4 + j) * 64 + (lane ^ (ks << 1))) * 8);
#pragma unroll
            for (int j = 0; j < 4; ++j) {
                acc[0][j] = __builtin_amdgcn_mfma_f32_16x16x32_bf16(a0, bfr[j], acc[0][j], 0, 0, 0);
                acc[1][j] = __builtin_amdgcn_mfma_f32_16x16x32_bf16(a1, bfr[j], acc[1][j], 0, 0, 0);
            }
        }
        // no trailing barrier: next iter writes the OTHER LDS buffer
    }

    // ---- epilogue: + bias, store fp32 ----
#pragma unroll
    for (int j = 0; j < 4; ++j) {
        const int n = n0 + j * 16 + ln;
        const float bv = bias[n];
#pragma unroll
        for (int i = 0; i < 2; ++i) {
            const int mbase = w * 32 + i * 16 + quad * 4;
#pragma unroll
            for (int rr = 0; rr < 4; ++rr)
                out[(size_t)(mbase + rr) * NN + n] = acc[i][j][rr] + bv;
        }
    }
}

extern "C" void kernel_launch(void* const* d_in, const int* in_sizes, int n_in,
                              void* d_out, int out_size, void* d_ws, size_t ws_size,
                              hipStream_t stream) {
    const float* x    = (const float*)d_in[0];
    const int* qw     = (const int*)d_in[1];
    const float* scl  = (const float*)d_in[2];
    const float* bias = (const float*)d_in[3];
    float* out        = (float*)d_out;

    dim3 grid(NN / BN);    // 256 blocks: one 64-col slab each, all 512 rows
    dim3 block(1024);      // 16 waves

    if (ws_size >= (size_t)MM * KK * sizeof(unsigned short)) {
        unsigned short* xp = (unsigned short*)d_ws;
        pack_x<<<dim3(MM * KK / (256 * 8)), dim3(256), 0, stream>>>(x, xp);
        qlin_gemm<true><<<grid, block, 0, stream>>>(x, xp, qw, scl, bias, out);
    } else {
        qlin_gemm<false><<<grid, block, 0, stream>>>(x, nullptr, qw, scl, bias, out);
    }
}